// Round 9
// baseline (89.472 us; speedup 1.0000x reference)
//
#include <hip/hip_runtime.h>

// DecodePredictions: YOLO-style decode, two-stage (R6 structure, PLAIN stores).
//   Stage A: one thread per anchor (134,400) -> 32B record in d_ws:
//            [x1, y1, x2, y2] and [sobj, 0, logit_ptr_lo, logit_ptr_hi]
//   Stage B: 15750 blocks x 256 threads, 4 plain float4 stores per thread,
//            load->store interleaved per iteration (R6's winning shape).
//   This round's single variable vs R6: __builtin_nontemporal_store -> plain.
//
// inputs (d_in order from setup_inputs):
//   [0] images (16,640,640,3) f32  -- only shape matters (H=W=640)
//   [1] pred0  (16,80,80,85)  f32
//   [2] pred1  (16,40,40,85)  f32
//   [3] pred2  (16,20,20,85)  f32
// output: (16, 8400*80, 6) f32 = 64,512,000 floats = 16,128,000 float4
//
// Record pattern per anchor: 120 float4, repeating every 3:
//   phase 0: [x1, y1, x2, y2]
//   phase 1: [2k, s_2k, x1, y1]
//   phase 2: [x2, y2, 2k+1, s_2k+1]

#define NANCH   8400      // 80*80 + 40*40 + 20*20
#define BATCH   16
#define NA      (BATCH * NANCH)   // 134,400 anchors
#define IMG     640.0f
#define NF4     16128000u         // out_size/4 = NA*120

typedef float vf4 __attribute__((ext_vector_type(4)));

__device__ __forceinline__ float fast_sigmoid(float v) {
    return __builtin_amdgcn_rcpf(1.0f + __expf(-v));
}

// ---------------- Stage A: per-anchor decode ----------------
__global__ __launch_bounds__(256) void anchor_kernel(
    const float* __restrict__ p0,
    const float* __restrict__ p1,
    const float* __restrict__ p2,
    vf4* __restrict__ ws)   // 2 vf4 per anchor
{
    const unsigned i = blockIdx.x * 256u + threadIdx.x;
    if (i >= NA) return;

    const unsigned b = i / NANCH;           // constant divisor -> magic mul
    const unsigned n = i - b * NANCH;

    const float* p;
    unsigned gx, gy;
    float stridef;
    if (n < 6400u) {            // 80x80, stride 8
        const unsigned loc = n;
        gx = loc % 80u; gy = loc / 80u;
        p = p0 + (size_t)(b * 6400u + loc) * 85u;
        stridef = 8.0f;
    } else if (n < 8000u) {     // 40x40, stride 16
        const unsigned loc = n - 6400u;
        gx = loc % 40u; gy = loc / 40u;
        p = p1 + (size_t)(b * 1600u + loc) * 85u;
        stridef = 16.0f;
    } else {                    // 20x20, stride 32
        const unsigned loc = n - 8000u;
        gx = loc % 20u; gy = loc / 20u;
        p = p2 + (size_t)(b * 400u + loc) * 85u;
        stridef = 32.0f;
    }

    const float px = p[0], py = p[1], pw = p[2], ph = p[3], pobj = p[4];
    const float inv = stridef * (1.0f / IMG);
    const float x = (px + (float)gx) * inv;
    const float y = (py + (float)gy) * inv;
    const float w = expf(pw) * inv;   // precise exp in tiny stage A
    const float h = expf(ph) * inv;

    const unsigned long long lp = (unsigned long long)(const void*)(p + 5);

    vf4 box; box.x = x * IMG; box.y = y * IMG; box.z = (x + w) * IMG; box.w = (y + h) * IMG;
    vf4 aux;
    aux.x = 1.0f / (1.0f + expf(-pobj));      // precise sigmoid for sobj
    aux.y = 0.0f;
    aux.z = __uint_as_float((unsigned)(lp & 0xffffffffull));
    aux.w = __uint_as_float((unsigned)(lp >> 32));
    ws[(size_t)i * 2u]      = box;
    ws[(size_t)i * 2u + 1u] = aux;
}

// ---------------- Stage B: output writer, 4 plain store streams/thread -----
__global__ __launch_bounds__(256) void write_kernel(
    const vf4* __restrict__ ws,
    vf4* __restrict__ out)
{
    const unsigned base = blockIdx.x * 1024u + threadIdx.x;

    #pragma unroll
    for (unsigned u = 0u; u < 4u; ++u) {
        const unsigned t = base + u * 256u;          // float4 index, coalesced
        const unsigned a = t / 120u;                 // anchor (magic mul)
        const unsigned j = t - a * 120u;
        const unsigned pair  = j / 3u;
        const unsigned phase = j - pair * 3u;

        const vf4 box = ws[(size_t)a * 2u];

        vf4 v;
        if (phase == 0u) {
            v = box;
        } else {
            const vf4 aux = ws[(size_t)a * 2u + 1u];
            const float* lp = (const float*)(
                (unsigned long long)__float_as_uint(aux.z) |
                ((unsigned long long)__float_as_uint(aux.w) << 32));
            const unsigned c = 2u * pair + (phase - 1u);
            const float sc = aux.x * fast_sigmoid(lp[c]);
            if (phase == 1u) { v.x = (float)c; v.y = sc;    v.z = box.x;    v.w = box.y; }
            else             { v.x = box.z;    v.y = box.w; v.z = (float)c; v.w = sc;   }
        }

        out[t] = v;   // PLAIN cached store — the single variable vs R6
    }
}

// ---------------- Fallback single kernel (if sizes mismatch) ----------------
__global__ __launch_bounds__(256) void decode_flat_kernel(
    const float* __restrict__ p0,
    const float* __restrict__ p1,
    const float* __restrict__ p2,
    float* __restrict__ out,
    unsigned nF4)
{
    const unsigned t = blockIdx.x * 256u + threadIdx.x;
    if (t >= nF4) return;
    const unsigned a = t / 120u;
    const unsigned j = t - a * 120u;
    const unsigned b = a / NANCH;
    const unsigned n = a - b * NANCH;

    const float* p;
    unsigned s, local;
    float stridef;
    if (n < 6400u) { s = 80u; local = n;        p = p0 + ((size_t)b * 6400u + local) * 85u; stridef = 8.0f; }
    else if (n < 8000u) { s = 40u; local = n - 6400u; p = p1 + ((size_t)b * 1600u + local) * 85u; stridef = 16.0f; }
    else { s = 20u; local = n - 8000u; p = p2 + ((size_t)b * 400u + local) * 85u; stridef = 32.0f; }
    const unsigned gx = local % s;
    const unsigned gy = local / s;
    const unsigned pair  = j / 3u;
    const unsigned phase = j - pair * 3u;

    const float px = p[0], py = p[1], pw = p[2], ph = p[3];
    const float inv = stridef * (1.0f / IMG);
    const float x = (px + (float)gx) * inv;
    const float y = (py + (float)gy) * inv;
    const float w = expf(pw) * inv;
    const float h = expf(ph) * inv;
    const float x1 = x * IMG, y1 = y * IMG, x2 = (x + w) * IMG, y2 = (y + h) * IMG;

    float4 v;
    if (phase == 0u) v = make_float4(x1, y1, x2, y2);
    else {
        const unsigned c = 2u * pair + (phase == 2u ? 1u : 0u);
        const float sc = (1.0f / (1.0f + expf(-p[4]))) * (1.0f / (1.0f + expf(-p[5u + c])));
        if (phase == 1u) v = make_float4((float)c, sc, x1, y1);
        else             v = make_float4(x2, y2, (float)c, sc);
    }
    reinterpret_cast<float4*>(out)[t] = v;
}

extern "C" void kernel_launch(void* const* d_in, const int* in_sizes, int n_in,
                              void* d_out, int out_size, void* d_ws, size_t ws_size,
                              hipStream_t stream) {
    const float* p0 = (const float*)d_in[1];
    const float* p1 = (const float*)d_in[2];
    const float* p2 = (const float*)d_in[3];

    const unsigned nF4 = (unsigned)(out_size / 4);        // 16,128,000
    const size_t ws_needed = (size_t)NA * 32u;            // 4,300,800 B

    if (ws_size >= ws_needed && nF4 == NF4) {
        vf4* ws = (vf4*)d_ws;
        anchor_kernel<<<(NA + 255u) / 256u, 256, 0, stream>>>(p0, p1, p2, ws);
        // 16,128,000 / 1024 = 15,750 blocks, exact
        write_kernel<<<NF4 / 1024u, 256, 0, stream>>>(ws, (vf4*)d_out);
    } else {
        decode_flat_kernel<<<(nF4 + 255u) / 256u, 256, 0, stream>>>(
            p0, p1, p2, (float*)d_out, nF4);
    }
}

// Round 10
// 49.066 us; speedup vs baseline: 1.8235x; 1.8235x over previous
//
#include <hip/hip_runtime.h>

// DecodePredictions: YOLO-style decode, FUSED fine-grained single kernel.
// 15,750 blocks x 256 threads; each block owns 1024 consecutive output float4s
// (slots blk*1024 .. +1023), which span <=10 anchors.
//   Phase 1: threads 0..(nA-1) decode one covering anchor each -> LDS:
//            [x1,y1,x2,y2] + [sobj, 0, logit_ptr_lo, logit_ptr_hi]
//   Phase 2: all 256 threads do 4 interleaved NT float4 stores (R6's shape).
//
// inputs (d_in order from setup_inputs):
//   [0] images (16,640,640,3) f32  -- only shape matters (H=W=640)
//   [1] pred0  (16,80,80,85)  f32
//   [2] pred1  (16,40,40,85)  f32
//   [3] pred2  (16,20,20,85)  f32
// output: (16, 8400*80, 6) f32 = 64,512,000 floats = 16,128,000 float4
//
// Record pattern per anchor: 120 float4, repeating every 3:
//   phase 0: [x1, y1, x2, y2]
//   phase 1: [2k, s_2k, x1, y1]
//   phase 2: [x2, y2, 2k+1, s_2k+1]

#define NANCH   8400      // 80*80 + 40*40 + 20*20
#define BATCH   16
#define NA      (BATCH * NANCH)   // 134,400 anchors
#define IMG     640.0f
#define NF4     16128000u         // out_size/4 = NA*120

typedef float vf4 __attribute__((ext_vector_type(4)));

__device__ __forceinline__ float fast_sigmoid(float v) {
    return __builtin_amdgcn_rcpf(1.0f + __expf(-v));
}

// ---------------- Fused fine-grained kernel ----------------
__global__ __launch_bounds__(256) void decode_stream_kernel(
    const float* __restrict__ p0,
    const float* __restrict__ p1,
    const float* __restrict__ p2,
    vf4* __restrict__ out)
{
    __shared__ vf4 rec[10][2];   // [local anchor][0]=box, [1]=aux

    const unsigned tid  = threadIdx.x;
    const unsigned blk  = blockIdx.x;
    const unsigned base = blk * 1024u;                    // first float4 slot
    const unsigned a0   = base / 120u;                    // first covering anchor
    const unsigned aN   = (base + 1023u) / 120u;          // last covering anchor

    // ---- Phase 1: decode covering anchors (<=10 threads active) ----
    if (tid <= (aN - a0)) {
        const unsigned i = a0 + tid;                      // global anchor id
        const unsigned b = i / NANCH;                     // magic mul
        const unsigned n = i - b * NANCH;

        const float* p;
        unsigned gx, gy;
        float stridef;
        if (n < 6400u) {            // 80x80, stride 8
            const unsigned loc = n;
            gx = loc % 80u; gy = loc / 80u;
            p = p0 + (size_t)(b * 6400u + loc) * 85u;
            stridef = 8.0f;
        } else if (n < 8000u) {     // 40x40, stride 16
            const unsigned loc = n - 6400u;
            gx = loc % 40u; gy = loc / 40u;
            p = p1 + (size_t)(b * 1600u + loc) * 85u;
            stridef = 16.0f;
        } else {                    // 20x20, stride 32
            const unsigned loc = n - 8000u;
            gx = loc % 20u; gy = loc / 20u;
            p = p2 + (size_t)(b * 400u + loc) * 85u;
            stridef = 32.0f;
        }

        const float px = p[0], py = p[1], pw = p[2], ph = p[3], pobj = p[4];
        const float inv = stridef * (1.0f / IMG);
        const float x = (px + (float)gx) * inv;
        const float y = (py + (float)gy) * inv;
        const float w = expf(pw) * inv;   // precise exp (few threads, cheap)
        const float h = expf(ph) * inv;

        const unsigned long long lp = (unsigned long long)(const void*)(p + 5);

        vf4 box; box.x = x * IMG; box.y = y * IMG; box.z = (x + w) * IMG; box.w = (y + h) * IMG;
        vf4 aux;
        aux.x = 1.0f / (1.0f + expf(-pobj));   // precise sigmoid for sobj
        aux.y = 0.0f;
        aux.z = __uint_as_float((unsigned)(lp & 0xffffffffull));
        aux.w = __uint_as_float((unsigned)(lp >> 32));
        rec[tid][0] = box;
        rec[tid][1] = aux;
    }
    __syncthreads();

    // ---- Phase 2: 4 interleaved NT store streams (R6's winning shape) ----
    #pragma unroll
    for (unsigned u = 0u; u < 4u; ++u) {
        const unsigned slot = u * 256u + tid;            // 0..1023
        const unsigned t    = base + slot;               // global float4 index
        const unsigned a    = t / 120u;                  // anchor (magic mul)
        const unsigned j    = t - a * 120u;
        const unsigned la   = a - a0;                    // local anchor
        const unsigned pair  = j / 3u;
        const unsigned phase = j - pair * 3u;

        const vf4 box = rec[la][0];

        vf4 v;
        if (phase == 0u) {
            v = box;
        } else {
            const vf4 aux = rec[la][1];
            const float* lp = (const float*)(
                (unsigned long long)__float_as_uint(aux.z) |
                ((unsigned long long)__float_as_uint(aux.w) << 32));
            const unsigned c = 2u * pair + (phase - 1u);
            const float sc = aux.x * fast_sigmoid(lp[c]);
            if (phase == 1u) { v.x = (float)c; v.y = sc;    v.z = box.x;    v.w = box.y; }
            else             { v.x = box.z;    v.y = box.w; v.z = (float)c; v.w = sc;   }
        }

        __builtin_nontemporal_store(v, &out[t]);
    }
}

// ---------------- Fallback single kernel (if sizes mismatch) ----------------
__global__ __launch_bounds__(256) void decode_flat_kernel(
    const float* __restrict__ p0,
    const float* __restrict__ p1,
    const float* __restrict__ p2,
    float* __restrict__ out,
    unsigned nF4)
{
    const unsigned t = blockIdx.x * 256u + threadIdx.x;
    if (t >= nF4) return;
    const unsigned a = t / 120u;
    const unsigned j = t - a * 120u;
    const unsigned b = a / NANCH;
    const unsigned n = a - b * NANCH;

    const float* p;
    unsigned s, local;
    float stridef;
    if (n < 6400u) { s = 80u; local = n;        p = p0 + ((size_t)b * 6400u + local) * 85u; stridef = 8.0f; }
    else if (n < 8000u) { s = 40u; local = n - 6400u; p = p1 + ((size_t)b * 1600u + local) * 85u; stridef = 16.0f; }
    else { s = 20u; local = n - 8000u; p = p2 + ((size_t)b * 400u + local) * 85u; stridef = 32.0f; }
    const unsigned gx = local % s;
    const unsigned gy = local / s;
    const unsigned pair  = j / 3u;
    const unsigned phase = j - pair * 3u;

    const float px = p[0], py = p[1], pw = p[2], ph = p[3];
    const float inv = stridef * (1.0f / IMG);
    const float x = (px + (float)gx) * inv;
    const float y = (py + (float)gy) * inv;
    const float w = expf(pw) * inv;
    const float h = expf(ph) * inv;
    const float x1 = x * IMG, y1 = y * IMG, x2 = (x + w) * IMG, y2 = (y + h) * IMG;

    float4 v;
    if (phase == 0u) v = make_float4(x1, y1, x2, y2);
    else {
        const unsigned c = 2u * pair + (phase == 2u ? 1u : 0u);
        const float sc = (1.0f / (1.0f + expf(-p[4]))) * (1.0f / (1.0f + expf(-p[5u + c])));
        if (phase == 1u) v = make_float4((float)c, sc, x1, y1);
        else             v = make_float4(x2, y2, (float)c, sc);
    }
    reinterpret_cast<float4*>(out)[t] = v;
}

extern "C" void kernel_launch(void* const* d_in, const int* in_sizes, int n_in,
                              void* d_out, int out_size, void* d_ws, size_t ws_size,
                              hipStream_t stream) {
    const float* p0 = (const float*)d_in[1];
    const float* p1 = (const float*)d_in[2];
    const float* p2 = (const float*)d_in[3];

    const unsigned nF4 = (unsigned)(out_size / 4);        // 16,128,000

    if (nF4 == NF4) {
        // 16,128,000 / 1024 = 15,750 blocks, exact; no bounds checks needed.
        decode_stream_kernel<<<NF4 / 1024u, 256, 0, stream>>>(
            p0, p1, p2, (vf4*)d_out);
    } else {
        decode_flat_kernel<<<(nF4 + 255u) / 256u, 256, 0, stream>>>(
            p0, p1, p2, (float*)d_out, nF4);
    }
}